// Round 3
// baseline (436.619 us; speedup 1.0000x reference)
//
#include <hip/hip_runtime.h>
#include <math.h>

typedef float f2 __attribute__((ext_vector_type(2)));
typedef float f2u __attribute__((ext_vector_type(2), aligned(4)));

#define BN 8
#define CIN 3
#define HH 512
#define WW 512
#define KK 9
#define OFFC 27
#define PATCH 27
#define NPAIR 13   // channel pairs (0,1)..(24,25); channel 26 handled scalar

// ws layout: pairs[i][q] (i=patch elem 0..26, q=pair 0..12) as float2, then w26[i] (27 floats)
__global__ void reorder_weights(const float* __restrict__ w_off, float* __restrict__ ws)
{
    const int t = threadIdx.x;
    if (t < PATCH * NPAIR) {
        const int i = t / NPAIR, q = t % NPAIR;
        ws[2 * t]     = w_off[(2 * q) * PATCH + i];
        ws[2 * t + 1] = w_off[(2 * q + 1) * PATCH + i];
    }
    if (t < PATCH) {
        ws[2 * PATCH * NPAIR + t] = w_off[26 * PATCH + t];
    }
}

__global__ __launch_bounds__(256) void deform_fused_kernel(
    const float* __restrict__ x,
    const float* __restrict__ wsw,    // reordered offset-conv weights (d_ws)
    const float* __restrict__ b_off,
    const float* __restrict__ w_def,
    const float* __restrict__ b_def,
    float* __restrict__ out)
{
    const int w = blockIdx.x * blockDim.x + threadIdx.x;
    const int h = blockIdx.y;
    const int b = blockIdx.z;

    const float* xb = x + (size_t)b * CIN * HH * WW;

    // ---- 3x3x3 zero-padded patch, flat index = c*9 + t ----
    float patch[PATCH];
    #pragma unroll
    for (int c = 0; c < CIN; ++c) {
        const float* xp = xb + (size_t)c * HH * WW;
        #pragma unroll
        for (int t = 0; t < KK; ++t) {
            const int yy = h + t / 3 - 1;
            const int xx = w + t % 3 - 1;
            const bool in = (yy >= 0) & (yy < HH) & (xx >= 0) & (xx < WW);
            patch[c * KK + t] = in ? xp[yy * WW + xx] : 0.0f;
        }
    }

    // ---- offset conv: 27 channels as 13 packed pairs + 1 scalar ----
    f2 owp[NPAIR];
    #pragma unroll
    for (int q = 0; q < NPAIR; ++q) {
        owp[q].x = b_off[2 * q];
        owp[q].y = b_off[2 * q + 1];
    }
    float ow26 = b_off[26];

    #pragma unroll
    for (int i = 0; i < PATCH; ++i) {
        const float p = patch[i];
        const f2 pp = { p, p };
        const f2* wrow = (const f2*)(wsw + i * (2 * NPAIR));
        #pragma unroll
        for (int q = 0; q < NPAIR; ++q) {
            owp[q] = __builtin_elementwise_fma(wrow[q], pp, owp[q]);
        }
        ow26 = fmaf(wsw[2 * PATCH * NPAIR + i], p, ow26);
    }

    // ---- deformable sampling + output contraction ----
    float acc0 = b_def[0];
    float acc1 = b_def[1];
    float acc2 = b_def[2];

    #pragma unroll
    for (int k = 0; k < KK; ++k) {
        const float oy = owp[k].x;
        const float ox = owp[k].y;
        const float om = (k < 8) ? ((k & 1) ? owp[9 + (k >> 1)].y
                                            : owp[9 + (k >> 1)].x)
                                 : ow26;

        const float m = 1.0f / (1.0f + __expf(-om));

        const float py = (float)h + (float)(k / 3 - 1) + oy;
        const float px = (float)w + (float)(k % 3 - 1) + ox;
        const float y0f = floorf(py);
        const float x0f = floorf(px);
        const float dy = py - y0f;
        const float dx = px - x0f;
        const int y0 = (int)y0f;
        const int x0 = (int)x0f;

        const f2 wTop = { (1.0f - dy) * (1.0f - dx), (1.0f - dy) * dx };
        const f2 wBot = { dy * (1.0f - dx), dy * dx };

        const int fast = (y0 >= 0) & (y0 + 1 < HH) & (x0 >= 0) & (x0 + 1 < WW);

        if (__all(fast)) {
            // whole wave's 2x2 footprints interior: unclamped paired loads
            const int idx = y0 * WW + x0;
            #pragma unroll
            for (int c = 0; c < CIN; ++c) {
                const float* xp = xb + (size_t)c * HH * WW + idx;
                const f2 vT = *(const f2u*)(xp);
                const f2 vB = *(const f2u*)(xp + WW);
                const f2 s = vT * wTop + vB * wBot;
                const float val = (s.x + s.y) * m;
                acc0 = fmaf(w_def[0 * PATCH + c * KK + k], val, acc0);
                acc1 = fmaf(w_def[1 * PATCH + c * KK + k], val, acc1);
                acc2 = fmaf(w_def[2 * PATCH + c * KK + k], val, acc2);
            }
        } else {
            // generic clamped path (correct for all lanes)
            const bool vy0 = (y0 >= 0)     & (y0 < HH);
            const bool vy1 = (y0 + 1 >= 0) & (y0 + 1 < HH);
            const bool vx0 = (x0 >= 0)     & (x0 < WW);
            const bool vx1 = (x0 + 1 >= 0) & (x0 + 1 < WW);

            const int yc0 = min(max(y0, 0), HH - 1);
            const int yc1 = min(max(y0 + 1, 0), HH - 1);
            const int xc0 = min(max(x0, 0), WW - 1);
            const int xc1 = min(max(x0 + 1, 0), WW - 1);

            #pragma unroll
            for (int c = 0; c < CIN; ++c) {
                const float* xp = xb + (size_t)c * HH * WW;
                const float v00 = (vy0 & vx0) ? xp[yc0 * WW + xc0] : 0.0f;
                const float v01 = (vy0 & vx1) ? xp[yc0 * WW + xc1] : 0.0f;
                const float v10 = (vy1 & vx0) ? xp[yc1 * WW + xc0] : 0.0f;
                const float v11 = (vy1 & vx1) ? xp[yc1 * WW + xc1] : 0.0f;

                const float val =
                    (v00 * wTop.x + v01 * wTop.y + v10 * wBot.x + v11 * wBot.y) * m;

                acc0 = fmaf(w_def[0 * PATCH + c * KK + k], val, acc0);
                acc1 = fmaf(w_def[1 * PATCH + c * KK + k], val, acc1);
                acc2 = fmaf(w_def[2 * PATCH + c * KK + k], val, acc2);
            }
        }
    }

    const size_t plane = (size_t)HH * WW;
    const size_t base = (size_t)b * (CIN * plane) + (size_t)h * WW + w;
    out[base]             = acc0;
    out[base + plane]     = acc1;
    out[base + 2 * plane] = acc2;
}

extern "C" void kernel_launch(void* const* d_in, const int* in_sizes, int n_in,
                              void* d_out, int out_size, void* d_ws, size_t ws_size,
                              hipStream_t stream) {
    const float* x     = (const float*)d_in[0];
    const float* w_off = (const float*)d_in[1];
    const float* b_off = (const float*)d_in[2];
    const float* w_def = (const float*)d_in[3];
    const float* b_def = (const float*)d_in[4];
    float* out = (float*)d_out;
    float* wsw = (float*)d_ws;   // 729 floats of reordered weights

    reorder_weights<<<1, 512, 0, stream>>>(w_off, wsw);

    dim3 block(256, 1, 1);
    dim3 grid(WW / 256, HH, BN);  // (2, 512, 8)
    deform_fused_kernel<<<grid, block, 0, stream>>>(x, wsw, b_off, w_def, b_def, out);
}

// Round 4
// 194.706 us; speedup vs baseline: 2.2424x; 2.2424x over previous
//
#include <hip/hip_runtime.h>
#include <math.h>

typedef float f4 __attribute__((ext_vector_type(4)));

#define BN 8
#define CIN 3
#define HH 512
#define WW 512
#define KK 9
#define OFFC 27
#define PATCH 27
#define TAPBLK 84   // per-tap weight block: wy[28] | wx[28] | wm[28], zero-padded

// ws layout: for k in 0..8: 84 floats = [wy_i]_{i<28} [wx_i]_{i<28} [wm_i]_{i<28}
// wy = channel 2k, wx = channel 2k+1, wm = channel 18+k; i = c*9+t patch index; pad i=27 -> 0
__global__ void reorder_weights(const float* __restrict__ w_off, float* __restrict__ ws)
{
    for (int idx = threadIdx.x; idx < KK * TAPBLK; idx += blockDim.x) {
        const int k = idx / TAPBLK;
        const int r = idx % TAPBLK;
        const int type = r / 28;
        const int i = r % 28;
        const int ch = (type == 0) ? 2 * k : (type == 1) ? 2 * k + 1 : 18 + k;
        ws[idx] = (i < PATCH) ? w_off[ch * PATCH + i] : 0.0f;
    }
}

__global__ __launch_bounds__(256) void deform_fused_kernel(
    const float* __restrict__ x,
    const float* __restrict__ wsw,    // reordered offset-conv weights (d_ws), 756 floats
    const float* __restrict__ b_off,
    const float* __restrict__ w_def,
    const float* __restrict__ b_def,
    float* __restrict__ out)
{
    __shared__ __attribute__((aligned(16))) float s_w[KK * TAPBLK];  // 756 floats
    __shared__ float s_boff[OFFC];
    __shared__ float s_wdef[3 * PATCH];
    __shared__ float s_bdef[3];

    for (int i = threadIdx.x; i < KK * TAPBLK; i += blockDim.x) s_w[i] = wsw[i];
    if (threadIdx.x < OFFC)      s_boff[threadIdx.x] = b_off[threadIdx.x];
    if (threadIdx.x < 3 * PATCH) s_wdef[threadIdx.x] = w_def[threadIdx.x];
    if (threadIdx.x < 3)         s_bdef[threadIdx.x] = b_def[threadIdx.x];
    __syncthreads();

    const int w = blockIdx.x * blockDim.x + threadIdx.x;
    const int h = blockIdx.y;
    const int b = blockIdx.z;
    if (w >= WW) return;

    const float* xb = x + (size_t)b * CIN * HH * WW;

    // ---- 3x3x3 zero-padded patch, flat index = c*9 + t; patch[27] = 0 (pad) ----
    float patch[28];
    patch[27] = 0.0f;
    #pragma unroll
    for (int c = 0; c < CIN; ++c) {
        const float* xp = xb + (size_t)c * HH * WW;
        #pragma unroll
        for (int t = 0; t < KK; ++t) {
            const int yy = h + t / 3 - 1;
            const int xx = w + t % 3 - 1;
            const bool in = (yy >= 0) & (yy < HH) & (xx >= 0) & (xx < WW);
            patch[c * KK + t] = in ? xp[yy * WW + xx] : 0.0f;
        }
    }

    float acc0 = s_bdef[0];
    float acc1 = s_bdef[1];
    float acc2 = s_bdef[2];

    #pragma unroll 1
    for (int k = 0; k < KK; ++k) {
        float oy = s_boff[2 * k];
        float ox = s_boff[2 * k + 1];
        float om = s_boff[18 + k];

        // per-tap weights: 21 x ds_read_b128
        const f4* wy4 = (const f4*)&s_w[k * TAPBLK];
        const f4* wx4 = (const f4*)&s_w[k * TAPBLK + 28];
        const f4* wm4 = (const f4*)&s_w[k * TAPBLK + 56];
        #pragma unroll
        for (int j = 0; j < 7; ++j) {
            const f4 a = wy4[j];
            const f4 bw = wx4[j];
            const f4 cw = wm4[j];
            #pragma unroll
            for (int l = 0; l < 4; ++l) {
                const float p = patch[4 * j + l];
                oy = fmaf(a[l],  p, oy);
                ox = fmaf(bw[l], p, ox);
                om = fmaf(cw[l], p, om);
            }
        }

        const float m = 1.0f / (1.0f + __expf(-om));

        const float py = (float)h + (float)(k / 3 - 1) + oy;
        const float px = (float)w + (float)(k % 3 - 1) + ox;
        const float y0f = floorf(py);
        const float x0f = floorf(px);
        const float dy = py - y0f;
        const float dx = px - x0f;
        const int y0 = (int)y0f;
        const int x0 = (int)x0f;

        const float w00 = (1.0f - dy) * (1.0f - dx);
        const float w01 = (1.0f - dy) * dx;
        const float w10 = dy * (1.0f - dx);
        const float w11 = dy * dx;

        const int interior = (y0 >= 0) & (y0 + 1 < HH) & (x0 >= 0) & (x0 + 1 < WW);

        if (__all(interior)) {
            // fast path: no clamps, no validity masks
            const int idx = y0 * WW + x0;
            #pragma unroll
            for (int c = 0; c < CIN; ++c) {
                const float* xp = xb + (size_t)c * HH * WW + idx;
                const float v00 = xp[0];
                const float v01 = xp[1];
                const float v10 = xp[WW];
                const float v11 = xp[WW + 1];
                const float val =
                    (v00 * w00 + v01 * w01 + v10 * w10 + v11 * w11) * m;
                acc0 = fmaf(s_wdef[0 * PATCH + c * KK + k], val, acc0);
                acc1 = fmaf(s_wdef[1 * PATCH + c * KK + k], val, acc1);
                acc2 = fmaf(s_wdef[2 * PATCH + c * KK + k], val, acc2);
            }
        } else {
            // generic clamped path (bit-identical to reference semantics)
            const bool vy0 = (y0 >= 0)     & (y0 < HH);
            const bool vy1 = (y0 + 1 >= 0) & (y0 + 1 < HH);
            const bool vx0 = (x0 >= 0)     & (x0 < WW);
            const bool vx1 = (x0 + 1 >= 0) & (x0 + 1 < WW);

            const int yc0 = min(max(y0, 0), HH - 1);
            const int yc1 = min(max(y0 + 1, 0), HH - 1);
            const int xc0 = min(max(x0, 0), WW - 1);
            const int xc1 = min(max(x0 + 1, 0), WW - 1);

            #pragma unroll
            for (int c = 0; c < CIN; ++c) {
                const float* xp = xb + (size_t)c * HH * WW;
                const float v00 = (vy0 & vx0) ? xp[yc0 * WW + xc0] : 0.0f;
                const float v01 = (vy0 & vx1) ? xp[yc0 * WW + xc1] : 0.0f;
                const float v10 = (vy1 & vx0) ? xp[yc1 * WW + xc0] : 0.0f;
                const float v11 = (vy1 & vx1) ? xp[yc1 * WW + xc1] : 0.0f;

                const float val =
                    (v00 * w00 + v01 * w01 + v10 * w10 + v11 * w11) * m;

                acc0 = fmaf(s_wdef[0 * PATCH + c * KK + k], val, acc0);
                acc1 = fmaf(s_wdef[1 * PATCH + c * KK + k], val, acc1);
                acc2 = fmaf(s_wdef[2 * PATCH + c * KK + k], val, acc2);
            }
        }
    }

    const size_t plane = (size_t)HH * WW;
    const size_t base = (size_t)b * (CIN * plane) + (size_t)h * WW + w;
    out[base]             = acc0;
    out[base + plane]     = acc1;
    out[base + 2 * plane] = acc2;
}

extern "C" void kernel_launch(void* const* d_in, const int* in_sizes, int n_in,
                              void* d_out, int out_size, void* d_ws, size_t ws_size,
                              hipStream_t stream) {
    const float* x     = (const float*)d_in[0];
    const float* w_off = (const float*)d_in[1];
    const float* b_off = (const float*)d_in[2];
    const float* w_def = (const float*)d_in[3];
    const float* b_def = (const float*)d_in[4];
    float* out = (float*)d_out;
    float* wsw = (float*)d_ws;   // 756 floats of reordered weights

    reorder_weights<<<1, 256, 0, stream>>>(w_off, wsw);

    dim3 block(256, 1, 1);
    dim3 grid(WW / 256, HH, BN);  // (2, 512, 8)
    deform_fused_kernel<<<grid, block, 0, stream>>>(x, wsw, b_off, w_def, b_def, out);
}